// Round 23
// baseline (131.163 us; speedup 1.0000x reference)
//
#include <hip/hip_runtime.h>
#include <hip/hip_bf16.h>

typedef unsigned short u16;
typedef __attribute__((ext_vector_type(4))) short bf16x4;
typedef __attribute__((ext_vector_type(8))) short bf16x8;
typedef __attribute__((ext_vector_type(16))) float f32x16;

#define NB_ 4
#define NT_ 2048
#define NC_ 768
#define NH_ 12
#define ND_ 64
#define NM_ (NB_*NT_)   // 8192 rows
#define KC_ 24          // K=768 -> 24 chunks of 32

// 1/sqrt(64) * log2(e): folded into q at the QKV epilogue -> attention runs in exp2 domain
#define SCQ_ 0.18033688011112042f

__device__ __forceinline__ u16 f2bf(float f){
  union { float f; unsigned u; } c; c.f = f;
  unsigned u = c.u;
  return (u16)((u + 0x7fffu + ((u>>16)&1u)) >> 16);  // RNE
}

__device__ __forceinline__ unsigned pkbf(float a, float b){
  __hip_bfloat162 h = __float22bfloat162_rn(make_float2(a,b));  // v_cvt_pk_bf16_f32
  union { __hip_bfloat162 h; unsigned u; } c; c.h = h; return c.u;
}

__device__ __forceinline__ f32x16 mfma32(bf16x8 a, bf16x8 b, f32x16 c){
  return __builtin_amdgcn_mfma_f32_32x32x16_bf16(a, b, c, 0, 0, 0);
}

__device__ __forceinline__ void gload_lds16(const void* g, void* l){
  __builtin_amdgcn_global_load_lds(
    (const __attribute__((address_space(1))) void*)g,
    (__attribute__((address_space(3))) void*)l, 16, 0, 0);
}

// PAN-panel blocked layout (GEMM operands):
//   off(row,k) = ((row/PAN)*KC_ + (k>>5))*(PAN*32) + ((k>>3)&3)*(PAN*8) + (row%PAN)*8 + (k&7)
// x, y use PAN=128; wa uses PAN=96 (gemmQ 96-col n-tiles); wp uses PAN=64 (gemmP 64-col).

// -------- fused preprocessing: cast x (blocked) + transpose wa (96) + wp (64) --------
__global__ __launch_bounds__(256) void prep_k(
    const float* __restrict__ x, const float* __restrict__ wa,
    const float* __restrict__ wp, u16* __restrict__ xb,
    u16* __restrict__ wat, u16* __restrict__ wpt){
  __shared__ float tile[32][33];
  const int bid = blockIdx.x, t = threadIdx.x;
  if (bid < 6144){
    int i = bid*256 + t;
    float4 v = ((const float4*)x)[i];
    int row = i / (NC_/4), k4 = (i % (NC_/4))*4;
    size_t off = (((size_t)(row>>7)*KC_ + (k4>>5))*4 + ((k4>>3)&3))*1024 + (row&127)*8 + (k4&7);
    bf16x4 o;
    o[0]=(short)f2bf(v.x); o[1]=(short)f2bf(v.y);
    o[2]=(short)f2bf(v.z); o[3]=(short)f2bf(v.w);
    *(bf16x4*)(xb + off) = o;
  } else {
    const float* in; u16* out; int c0, r0, Cc, PAN;
    if (bid < 6144 + 1728){           // wa: [768][2304] -> 96-panel blocked
      int b = bid - 6144;
      in = wa; out = wat; Cc = 3*NC_; PAN = 96;
      c0 = (b % 72)*32; r0 = (b / 72)*32;
    } else {                          // wp: [768][768] -> 64-panel blocked
      int b = bid - 7872;
      in = wp; out = wpt; Cc = NC_; PAN = 64;
      c0 = (b % 24)*32; r0 = (b / 24)*32;
    }
    int tx = t & 31, ty = t >> 5;     // 32 x 8
    #pragma unroll
    for (int j=0;j<32;j+=8) tile[ty+j][tx] = in[(size_t)(r0+ty+j)*Cc + c0+tx];
    __syncthreads();
    #pragma unroll
    for (int j=0;j<32;j+=8){
      int n = c0+ty+j, k = r0+tx;
      size_t off = ((size_t)(n/PAN)*KC_ + (k>>5))*(PAN*32)
                 + (size_t)((k>>3)&3)*(PAN*8) + (n%PAN)*8 + (k&7);
      out[off] = f2bf(tile[tx][ty+j]);
    }
  }
}

// ---------------- gemmQ: qkv GEMM, 256x96 block, 4 waves x (64m x 96n) ----------------
// 768 blocks = exactly 3/CU, all co-resident. 2-buf top-barrier. Scatters q*scale /
// k (64-chunk slot-major) / v (sigma-permuted, 64-chunk slot-major).
__global__ __launch_bounds__(256,3) void gemmQ(
  const u16* __restrict__ A, const u16* __restrict__ BT, const float* __restrict__ bias,
  u16* __restrict__ qo, u16* __restrict__ ko, u16* __restrict__ vo)
{
  __shared__ u16 lds[2][11264];   // [buf][ A-pan0 4096 | A-pan1 4096 | B 3072 ], 44 KB
  const int t = threadIdx.x, w = t>>6, l = t&63;
  const int lq = l&31, h = l>>5;
  int sw = (blockIdx.x & 7)*96 + (blockIdx.x >> 3);
  const int rb = sw / 24, nb = sw % 24;       // 32 rb x 24 nb
  const int brow = rb*256, bcol = nb*96;

  f32x16 acc[2][3];
  #pragma unroll
  for (int i=0;i<2;i++)
    #pragma unroll
    for (int j=0;j<3;j++)
      #pragma unroll
      for (int r=0;r<16;r++) acc[i][j][r] = 0.f;

  auto stage = [&](int buf, int kc){
    const u16* A0 = A  + ((size_t)((rb*2  )*KC_ + kc))*4096;
    const u16* A1 = A  + ((size_t)((rb*2+1)*KC_ + kc))*4096;
    const u16* Bg = BT + ((size_t)(nb*KC_ + kc))*3072;
    char* L = (char*)&lds[buf][0];
    gload_lds16(A0 + t*8,         L + t*16);
    gload_lds16(A0 + (256+t)*8,   L + (256+t)*16);
    gload_lds16(A1 + t*8,         L + 8192  + t*16);
    gload_lds16(A1 + (256+t)*8,   L + 8192  + (256+t)*16);
    gload_lds16(Bg + t*8,         L + 16384 + t*16);
    if (t < 128)
      gload_lds16(Bg + (256+t)*8, L + 16384 + (256+t)*16);
  };

  stage(0,0);
  int cur = 0;
  for (int kc=0; kc<KC_; ++kc){
    asm volatile("s_waitcnt vmcnt(0)\ns_barrier" ::: "memory");
    if (kc+1 < KC_) stage(cur^1, kc+1);
    const u16* La = &lds[cur][(w>>1)*4096];   // this wave's A panel
    const u16* Lb = &lds[cur][8192];
    #pragma unroll
    for (int ks=0; ks<2; ++ks){
      bf16x8 af[2], bfr[3];
      #pragma unroll
      for (int mi=0;mi<2;mi++)
        af[mi]  = *(const bf16x8*)(La + ((2*ks+h)*128 + (w&1)*64 + mi*32 + lq)*8);
      #pragma unroll
      for (int nj=0;nj<3;nj++)
        bfr[nj] = *(const bf16x8*)(Lb + ((2*ks+h)*96 + nj*32 + lq)*8);
      __builtin_amdgcn_s_setprio(1);
      #pragma unroll
      for (int mi=0;mi<2;mi++)
        #pragma unroll
        for (int nj=0;nj<3;nj++)
          acc[mi][nj] = mfma32(af[mi], bfr[nj], acc[mi][nj]);
      __builtin_amdgcn_s_setprio(0);
    }
    cur ^= 1;
  }

  // C/D map: col(n) = lq, row(m) offset = (r&3) + 8*(r>>2) + 4*h
  const int sec = nb >> 3;                    // 8 x 96-col blocks per q/k/v section
  u16* outp = (sec==0) ? qo : (sec==1 ? ko : vo);
  #pragma unroll
  for (int nj=0;nj<3;nj++){
    int n = bcol + nj*32 + lq;
    int cc = n - sec*NC_;
    int hd = cc >> 6, d = cc & 63;
    float bs = bias[n];
    #pragma unroll
    for (int mi=0;mi<2;mi++)
      #pragma unroll
      for (int r=0;r<16;r++){
        int m = brow + w*64 + mi*32 + (r&3) + 8*(r>>2) + 4*h;
        int bb = m >> 11, tt = m & 2047;
        float v = acc[mi][nj][r] + bs;
        if (sec == 0) v *= SCQ_;              // pre-scale q for exp2-domain attn
        size_t bhbase = ((size_t)bb*NH_ + hd)*((size_t)NT_*ND_);
        size_t off;
        if (sec == 0){
          off = bhbase + (size_t)tt*ND_ + d;                 // q [B,H,T,D]
        } else if (sec == 1){
          // k slot-major: [chunk=tt>>6][slot=d>>3][row=tt&63][el=d&7]
          off = bhbase + (size_t)(tt>>6)*4096 + (size_t)(d>>3)*512 + (tt&63)*8 + (d&7);
        } else {
          // v^T, kv sigma-permuted within 16-blocks, slot-major over position p
          int p = (tt & ~15) | (h<<3) | (r&3) | (((r>>2)&1)<<2);
          off = bhbase + (size_t)(p>>6)*4096 + (size_t)((p&63)>>3)*512 + d*8 + (p&7);
        }
        outp[off] = f2bf(v);
      }
  }
}

// ---------------- gemmP: proj GEMM, 128x64 block, 768 blocks = exactly 3/CU ----------
__global__ __launch_bounds__(256,3) void gemmP(
  const u16* __restrict__ A, const u16* __restrict__ BT, const float* __restrict__ bias,
  float* __restrict__ fo)
{
  __shared__ u16 lds[2][6144];    // [buf][ A 128x32 (4096) | B 64x32 (2048) ], 24 KB
  const int t = threadIdx.x, w = t>>6, l = t&63;
  const int lq = l&31, h = l>>5;
  int sw = (blockIdx.x & 7)*96 + (blockIdx.x >> 3);   // 768 % 8 == 0
  const int rb = sw / 12, nb = sw % 12;
  const int brow = rb*128, bcol = nb*64;
  const int wr = (w>>1)*64, wc = (w&1)*32;

  f32x16 acc[2];
  #pragma unroll
  for (int i=0;i<2;i++)
    #pragma unroll
    for (int r=0;r<16;r++) acc[i][r] = 0.f;

  auto stage = [&](int buf, int kc){
    const u16* Ag = A  + ((size_t)(rb*KC_ + kc))*4096;
    const u16* Bg = BT + ((size_t)(nb*KC_ + kc))*2048;
    char* La = (char*)&lds[buf][0];
    char* Lb = (char*)&lds[buf][4096];
    #pragma unroll
    for (int it=0; it<2; ++it)
      gload_lds16(Ag + (it*256+t)*8, La + (it*256+t)*16);
    gload_lds16(Bg + t*8, Lb + t*16);
  };

  stage(0,0);
  int cur = 0;
  for (int kc=0; kc<KC_; ++kc){
    asm volatile("s_waitcnt vmcnt(0)\ns_barrier" ::: "memory");
    if (kc+1 < KC_) stage(cur^1, kc+1);
    const u16* La = &lds[cur][0];
    const u16* Lb = &lds[cur][4096];
    #pragma unroll
    for (int ks=0; ks<2; ++ks){
      bf16x8 af[2], bfr;
      #pragma unroll
      for (int mi=0;mi<2;mi++)
        af[mi] = *(const bf16x8*)(La + ((2*ks+h)*128 + wr + mi*32 + lq)*8);
      bfr = *(const bf16x8*)(Lb + ((2*ks+h)*64 + wc + lq)*8);
      __builtin_amdgcn_s_setprio(1);
      #pragma unroll
      for (int mi=0;mi<2;mi++)
        acc[mi] = mfma32(af[mi], bfr, acc[mi]);
      __builtin_amdgcn_s_setprio(0);
    }
    cur ^= 1;
  }

  {
    int n = bcol + wc + lq;
    float bs = bias[n];
    #pragma unroll
    for (int mi=0;mi<2;mi++)
      #pragma unroll
      for (int r=0;r<16;r++){
        int m = brow + wr + mi*32 + (r&3) + 8*(r>>2) + 4*h;
        fo[(size_t)m*NC_ + n] = acc[mi][r] + bs;
      }
  }
}

// ---------------- flash attention v23: QBLK=256 (8 waves x 32 q) -- halve staging ----
// r22's decisive datapoint: doubling occupancy/waves/LDS-reads left attn at 58.2us.
// Conserved across ALL ~58us variants: total staged bytes (209MB) and gload_lds count
// (~52K insts/CU ~= 2.7cy each = 139K cyc = 58us) -> staging THROUGHPUT is binding.
// Re-staging is quadratic in tiles-per-bh: QBLK 128->256 halves it (per-bh sum nc
// 272->144, 209->107MB). Grid 384: heavy tiles (qt7,6,+1/3 of 5) are SINGLES on CUs
// 128-255; light tiles pair on CUs 0-127 (pair sums <=36 periods). All group bases
// = 0 mod 8 -> XCD = bh%8 (L2 locality); all blocks start at chunk 0 (lockstep reuse).
// Data path identical to r13/r20: 2-buf 32KB top-barrier, slot-major staging, no-max
// exp2 softmax, ones-MFMA lsum, P feeds PV in-lane.
__global__ __launch_bounds__(512,2) void attn_kernel(
    const u16* __restrict__ qg, const u16* __restrict__ kg,
    const u16* __restrict__ vg, u16* __restrict__ y)
{
  __shared__ u16 lds[2][8192];    // [buf][ K 4096 el | V 4096 el ], 32 KB
  const int t = threadIdx.x, w = t>>6, l = t&63;
  const int lq = l&31, h = l>>5;
  const int bid = blockIdx.x;
  int qt, bh;
  if (bid < 128){                 // light doubles, first slot (CUs 0-127)
    if (bid < 16)       { qt = 5; bh = 32 + bid; }
    else if (bid < 64)  { qt = 4; bh = bid - 16; }
    else if (bid < 112) { qt = 3; bh = bid - 64; }
    else                { qt = 2; bh = bid - 112; }
  } else if (bid < 256){          // heavy singles (CUs 128-255)
    if (bid < 176)      { qt = 7; bh = bid - 128; }
    else if (bid < 224) { qt = 6; bh = bid - 176; }
    else                { qt = 5; bh = bid - 224; }
  } else {                        // light doubles, second slot (CUs 0-127)
    if (bid < 288)      { qt = 2; bh = 16 + (bid - 256); }
    else if (bid < 336) { qt = 1; bh = bid - 288; }
    else                { qt = 0; bh = bid - 336; }
  }
  const int bb = bh / NH_, hh = bh % NH_;
  const u16* qp = qg + (size_t)bh*NT_*ND_;
  const u16* kp = kg + (size_t)bh*NT_*ND_;    // slot-major chunked
  const u16* vp = vg + (size_t)bh*NT_*ND_;    // slot-major chunked, kv-permuted
  const int qmin = qt*256 + w*32;
  const int q = qmin + lq;        // this lane's q row (column of S^T)

  // Q frags (pi-permuted): slot i of k-block ks holds Q[q][ks*16 + 8h + i]
  bf16x8 Qf[4];
  {
    const u16* qr = qp + (size_t)q*ND_ + 8*h;
    #pragma unroll
    for (int ks=0; ks<4; ++ks) Qf[ks] = *(const bf16x8*)(qr + ks*16);
  }
  bf16x8 ones;
  #pragma unroll
  for (int i=0;i<8;i++) ones[i] = (short)0x3F80;   // bf16 1.0

  f32x16 o0, o1, ls;              // O^T acc + lsum acc (all ls rows identical)
  #pragma unroll
  for (int r=0;r<16;r++){ o0[r]=0.f; o1[r]=0.f; ls[r]=0.f; }
  const int nc = 4*qt + 4;        // 64-kv chunks covering this block's 256 q

  auto stage = [&](int buf, int c){
    const u16* kc2 = kp + c*4096;
    const u16* vc2 = vp + c*4096;
    gload_lds16(kc2 + t*8, (char*)&lds[buf][0]    + t*16);
    gload_lds16(vc2 + t*8, (char*)&lds[buf][4096] + t*16);
  };

  stage(0,0);
  int cur = 0;
  for (int c=0; c<nc; ++c){
    // waits only on stage(c) (one iteration old -> landed); stage(c+1) issued after
    asm volatile("s_waitcnt vmcnt(0)\ns_barrier" ::: "memory");
    if (c+1 < nc) stage(cur^1, c+1);

    const int kv0 = c*64;
    if (kv0 <= qmin + 31){        // wave-uniform: skip fully-masked chunks
      const u16* Kb = &lds[cur][0];
      const u16* Vb = &lds[cur][4096];

      // S^T (64 kv x 32 q), q pre-scaled -> exp2 domain
      f32x16 s0, s1;
      #pragma unroll
      for (int r=0;r<16;r++){ s0[r]=0.f; s1[r]=0.f; }
      __builtin_amdgcn_s_setprio(1);
      #pragma unroll
      for (int ks=0; ks<4; ++ks){
        bf16x8 k0 = *(const bf16x8*)(Kb + ((2*ks+h)*64      + lq)*8);
        bf16x8 k1 = *(const bf16x8*)(Kb + ((2*ks+h)*64 + 32 + lq)*8);
        s0 = mfma32(k0, Qf[ks], s0);
        s1 = mfma32(k1, Qf[ks], s1);
      }
      __builtin_amdgcn_s_setprio(0);

      // causal mask: wave-uniform branch; diagonal chunks only
      if (kv0 + 63 > qmin){
        #pragma unroll
        for (int r=0;r<16;r++){
          int kva = kv0 + (r&3) + 8*(r>>2) + 4*h;
          s0[r] = (kva      <= q) ? s0[r] : -3e38f;
          s1[r] = (kva + 32 <= q) ? s1[r] : -3e38f;
        }
      }

      // P = exp2(s); pack pairs (masked -> exp2(-3e38) = 0)
      union { unsigned wd[16]; bf16x8 v[4]; } pf;
      #pragma unroll
      for (int j=0;j<8;j++)
        pf.wd[j]   = pkbf(exp2f(s0[2*j]), exp2f(s0[2*j+1]));
      #pragma unroll
      for (int j=0;j<8;j++)
        pf.wd[8+j] = pkbf(exp2f(s1[2*j]), exp2f(s1[2*j+1]));

      // PV + lsum: O^T += V^T * P^T ; ls += ones * P^T (row sum of P per q)
      __builtin_amdgcn_s_setprio(1);
      #pragma unroll
      for (int j=0;j<4;j++){
        bf16x8 v0 = *(const bf16x8*)(Vb + ((2*j+h)*64      + lq)*8);
        bf16x8 v1 = *(const bf16x8*)(Vb + ((2*j+h)*64 + 32 + lq)*8);
        o0 = mfma32(v0, pf.v[j], o0);
        o1 = mfma32(v1, pf.v[j], o1);
        ls = mfma32(ones, pf.v[j], ls);
      }
      __builtin_amdgcn_s_setprio(0);
    }
    cur ^= 1;
  }

  float inv = 1.f / ls[0];        // full kv-sum for this lane's q

  // epilogue: y in 128-panel blocked layout for proj: row m = bb*NT+q, k = hh*64+d
  const int m = bb*NT_ + q;
  const int rbm = m>>7, rr = m&127;
  #pragma unroll
  for (int db=0; db<2; ++db){
    #pragma unroll
    for (int g2=0; g2<4; ++g2){
      float e0 = (db ? o1[g2*4+0] : o0[g2*4+0]) * inv;
      float e1 = (db ? o1[g2*4+1] : o0[g2*4+1]) * inv;
      float e2 = (db ? o1[g2*4+2] : o0[g2*4+2]) * inv;
      float e3 = (db ? o1[g2*4+3] : o0[g2*4+3]) * inv;
      unsigned w0 = pkbf(e0,e1), w1 = pkbf(e2,e3);
      int k = hh*ND_ + db*32 + g2*8 + 4*h;
      size_t off = (((size_t)rbm*KC_ + (k>>5))*4 + ((k>>3)&3))*1024 + rr*8 + (k&7);
      *(uint2*)(y + off) = make_uint2(w0, w1);
    }
  }
}

// ---------------- launch ----------------
extern "C" void kernel_launch(void* const* d_in, const int* in_sizes, int n_in,
                              void* d_out, int out_size, void* d_ws, size_t ws_size,
                              hipStream_t stream) {
  const float* x  = (const float*)d_in[0];
  const float* wa = (const float*)d_in[1];
  const float* ba = (const float*)d_in[2];
  const float* wp = (const float*)d_in[3];
  const float* bp = (const float*)d_in[4];
  float* out = (float*)d_out;

  char* ws = (char*)d_ws;
  const size_t szXB = (size_t)NM_*NC_*2;        // 12,582,912
  const size_t szWA = (size_t)3*NC_*NC_*2;      //  3,538,944
  const size_t szWP = (size_t)NC_*NC_*2;        //  1,179,648
  const size_t szQ  = szXB;
  u16* xb  = (u16*)(ws);
  u16* wat = (u16*)(ws + szXB);
  u16* wpt = (u16*)(ws + szXB + szWA);
  u16* qb  = (u16*)(ws + szXB + szWA + szWP);
  u16* kb  = (u16*)((char*)qb + szQ);
  u16* vb  = (u16*)((char*)kb + szQ);
  u16* yb  = xb;    // reuse x-slot: attn writes y after gemmQ consumed xb

  // 1) fused preprocessing: cast x + transpose wa(96) + wp(64)  (one launch)
  prep_k<<<dim3(6144 + 1728 + 576), dim3(256), 0, stream>>>(x, wa, wp, xb, wat, wpt);
  // 2) qkv = x @ w_attn + b_attn  -> q*scale, k/v slot-major scattered (768 blocks)
  gemmQ<<<dim3(768), dim3(256), 0, stream>>>(xb, wat, ba, qb, kb, vb);
  // 3) flash attention -> y (blocked) bf16; 384 blocks x 8 waves x 32 q (QBLK=256)
  attn_kernel<<<dim3(384), dim3(512), 0, stream>>>(qb, kb, vb, yb);
  // 4) out = y @ w_proj + b_proj (f32); 768 blocks, exactly 3/CU
  gemmP<<<dim3(768), dim3(256), 0, stream>>>(yb, wpt, bp, out);
}

// Round 24
// 125.406 us; speedup vs baseline: 1.0459x; 1.0459x over previous
//
#include <hip/hip_runtime.h>
#include <hip/hip_bf16.h>

typedef unsigned short u16;
typedef __attribute__((ext_vector_type(4))) short bf16x4;
typedef __attribute__((ext_vector_type(8))) short bf16x8;
typedef __attribute__((ext_vector_type(4))) float f32x4;
typedef __attribute__((ext_vector_type(16))) float f32x16;

#define NB_ 4
#define NT_ 2048
#define NC_ 768
#define NH_ 12
#define ND_ 64
#define NM_ (NB_*NT_)   // 8192 rows
#define KC_ 24          // K=768 -> 24 chunks of 32

// 1/sqrt(64) * log2(e): folded into q at the QKV epilogue -> attention runs in exp2 domain
#define SCQ_ 0.18033688011112042f

__device__ __forceinline__ u16 f2bf(float f){
  union { float f; unsigned u; } c; c.f = f;
  unsigned u = c.u;
  return (u16)((u + 0x7fffu + ((u>>16)&1u)) >> 16);  // RNE
}

__device__ __forceinline__ unsigned pkbf(float a, float b){
  __hip_bfloat162 h = __float22bfloat162_rn(make_float2(a,b));  // v_cvt_pk_bf16_f32
  union { __hip_bfloat162 h; unsigned u; } c; c.h = h; return c.u;
}

__device__ __forceinline__ f32x4 mfma16(bf16x8 a, bf16x8 b, f32x4 c){
  return __builtin_amdgcn_mfma_f32_16x16x32_bf16(a, b, c, 0, 0, 0);
}
__device__ __forceinline__ f32x16 mfma32(bf16x8 a, bf16x8 b, f32x16 c){
  return __builtin_amdgcn_mfma_f32_32x32x16_bf16(a, b, c, 0, 0, 0);
}

__device__ __forceinline__ void gload_lds16(const void* g, void* l){
  __builtin_amdgcn_global_load_lds(
    (const __attribute__((address_space(1))) void*)g,
    (__attribute__((address_space(3))) void*)l, 16, 0, 0);
}

// PAN-panel blocked layout (GEMM operands):
//   off(row,k) = ((row/PAN)*KC_ + (k>>5))*(PAN*32) + ((k>>3)&3)*(PAN*8) + (row%PAN)*8 + (k&7)
// x, y use PAN=128; wa uses PAN=96 (gemmQ 96-col n-tiles); wp uses PAN=64 (gemmP 64-col).

// -------- fused preprocessing: cast x (blocked) + transpose wa (96) + wp (64) --------
__global__ __launch_bounds__(256) void prep_k(
    const float* __restrict__ x, const float* __restrict__ wa,
    const float* __restrict__ wp, u16* __restrict__ xb,
    u16* __restrict__ wat, u16* __restrict__ wpt){
  __shared__ float tile[32][33];
  const int bid = blockIdx.x, t = threadIdx.x;
  if (bid < 6144){
    int i = bid*256 + t;
    float4 v = ((const float4*)x)[i];
    int row = i / (NC_/4), k4 = (i % (NC_/4))*4;
    size_t off = (((size_t)(row>>7)*KC_ + (k4>>5))*4 + ((k4>>3)&3))*1024 + (row&127)*8 + (k4&7);
    bf16x4 o;
    o[0]=(short)f2bf(v.x); o[1]=(short)f2bf(v.y);
    o[2]=(short)f2bf(v.z); o[3]=(short)f2bf(v.w);
    *(bf16x4*)(xb + off) = o;
  } else {
    const float* in; u16* out; int c0, r0, Cc, PAN;
    if (bid < 6144 + 1728){           // wa: [768][2304] -> 96-panel blocked
      int b = bid - 6144;
      in = wa; out = wat; Cc = 3*NC_; PAN = 96;
      c0 = (b % 72)*32; r0 = (b / 72)*32;
    } else {                          // wp: [768][768] -> 64-panel blocked
      int b = bid - 7872;
      in = wp; out = wpt; Cc = NC_; PAN = 64;
      c0 = (b % 24)*32; r0 = (b / 24)*32;
    }
    int tx = t & 31, ty = t >> 5;     // 32 x 8
    #pragma unroll
    for (int j=0;j<32;j+=8) tile[ty+j][tx] = in[(size_t)(r0+ty+j)*Cc + c0+tx];
    __syncthreads();
    #pragma unroll
    for (int j=0;j<32;j+=8){
      int n = c0+ty+j, k = r0+tx;
      size_t off = ((size_t)(n/PAN)*KC_ + (k>>5))*(PAN*32)
                 + (size_t)((k>>3)&3)*(PAN*8) + (n%PAN)*8 + (k&7);
      out[off] = f2bf(tile[tx][ty+j]);
    }
  }
}

// ---------------- gemmQ: qkv GEMM, 256x96 block, 4 waves x (64m x 96n) ----------------
// 768 blocks = exactly 3/CU, all co-resident. 2-buf top-barrier. Scatters q*scale /
// k (64-chunk slot-major) / v (sigma'-permuted for the 16x16 PV path, slot-major).
__global__ __launch_bounds__(256,3) void gemmQ(
  const u16* __restrict__ A, const u16* __restrict__ BT, const float* __restrict__ bias,
  u16* __restrict__ qo, u16* __restrict__ ko, u16* __restrict__ vo)
{
  __shared__ u16 lds[2][11264];   // [buf][ A-pan0 4096 | A-pan1 4096 | B 3072 ], 44 KB
  const int t = threadIdx.x, w = t>>6, l = t&63;
  const int lq = l&31, h = l>>5;
  int sw = (blockIdx.x & 7)*96 + (blockIdx.x >> 3);
  const int rb = sw / 24, nb = sw % 24;       // 32 rb x 24 nb
  const int brow = rb*256, bcol = nb*96;

  f32x16 acc[2][3];
  #pragma unroll
  for (int i=0;i<2;i++)
    #pragma unroll
    for (int j=0;j<3;j++)
      #pragma unroll
      for (int r=0;r<16;r++) acc[i][j][r] = 0.f;

  auto stage = [&](int buf, int kc){
    const u16* A0 = A  + ((size_t)((rb*2  )*KC_ + kc))*4096;
    const u16* A1 = A  + ((size_t)((rb*2+1)*KC_ + kc))*4096;
    const u16* Bg = BT + ((size_t)(nb*KC_ + kc))*3072;
    char* L = (char*)&lds[buf][0];
    gload_lds16(A0 + t*8,         L + t*16);
    gload_lds16(A0 + (256+t)*8,   L + (256+t)*16);
    gload_lds16(A1 + t*8,         L + 8192  + t*16);
    gload_lds16(A1 + (256+t)*8,   L + 8192  + (256+t)*16);
    gload_lds16(Bg + t*8,         L + 16384 + t*16);
    if (t < 128)
      gload_lds16(Bg + (256+t)*8, L + 16384 + (256+t)*16);
  };

  stage(0,0);
  int cur = 0;
  for (int kc=0; kc<KC_; ++kc){
    asm volatile("s_waitcnt vmcnt(0)\ns_barrier" ::: "memory");
    if (kc+1 < KC_) stage(cur^1, kc+1);
    const u16* La = &lds[cur][(w>>1)*4096];   // this wave's A panel
    const u16* Lb = &lds[cur][8192];
    #pragma unroll
    for (int ks=0; ks<2; ++ks){
      bf16x8 af[2], bfr[3];
      #pragma unroll
      for (int mi=0;mi<2;mi++)
        af[mi]  = *(const bf16x8*)(La + ((2*ks+h)*128 + (w&1)*64 + mi*32 + lq)*8);
      #pragma unroll
      for (int nj=0;nj<3;nj++)
        bfr[nj] = *(const bf16x8*)(Lb + ((2*ks+h)*96 + nj*32 + lq)*8);
      __builtin_amdgcn_s_setprio(1);
      #pragma unroll
      for (int mi=0;mi<2;mi++)
        #pragma unroll
        for (int nj=0;nj<3;nj++)
          acc[mi][nj] = mfma32(af[mi], bfr[nj], acc[mi][nj]);
      __builtin_amdgcn_s_setprio(0);
    }
    cur ^= 1;
  }

  // C/D map: col(n) = lq, row(m) offset = (r&3) + 8*(r>>2) + 4*h
  const int sec = nb >> 3;                    // 8 x 96-col blocks per q/k/v section
  u16* outp = (sec==0) ? qo : (sec==1 ? ko : vo);
  #pragma unroll
  for (int nj=0;nj<3;nj++){
    int n = bcol + nj*32 + lq;
    int cc = n - sec*NC_;
    int hd = cc >> 6, d = cc & 63;
    float bs = bias[n];
    #pragma unroll
    for (int mi=0;mi<2;mi++)
      #pragma unroll
      for (int r=0;r<16;r++){
        int m = brow + w*64 + mi*32 + (r&3) + 8*(r>>2) + 4*h;
        int bb = m >> 11, tt = m & 2047;
        float v = acc[mi][nj][r] + bs;
        if (sec == 0) v *= SCQ_;              // pre-scale q for exp2-domain attn
        size_t bhbase = ((size_t)bb*NH_ + hd)*((size_t)NT_*ND_);
        size_t off;
        if (sec == 0){
          off = bhbase + (size_t)tt*ND_ + d;                 // q [B,H,T,D]
        } else if (sec == 1){
          // k slot-major: [chunk=tt>>6][slot=d>>3][row=tt&63][el=d&7]
          off = bhbase + (size_t)(tt>>6)*4096 + (size_t)(d>>3)*512 + (tt&63)*8 + (d&7);
        } else {
          // v^T sigma' for 16x16 PV: within each 32-kv window, storage pos
          // p5 = g'*8 + half*4 + j where kv5 = 16*half + 4*g' + j.
          // Here kv5 = (r&3) + 8*(r>>2) + 4*h -> j=r&3, g'=(2*(r>>2)+h)&3, half=(r>>3)&1.
          int g2 = (2*(r>>2) + h) & 3;
          int p = (tt & ~31) | (g2<<3) | (((r>>3)&1)<<2) | (r&3);
          off = bhbase + (size_t)(p>>6)*4096 + (size_t)((p&63)>>3)*512 + d*8 + (p&7);
        }
        outp[off] = f2bf(v);
      }
  }
}

// ---------------- gemmP: proj GEMM, 128x64 block, 768 blocks = exactly 3/CU ----------
__global__ __launch_bounds__(256,3) void gemmP(
  const u16* __restrict__ A, const u16* __restrict__ BT, const float* __restrict__ bias,
  float* __restrict__ fo)
{
  __shared__ u16 lds[2][6144];    // [buf][ A 128x32 (4096) | B 64x32 (2048) ], 24 KB
  const int t = threadIdx.x, w = t>>6, l = t&63;
  const int lq = l&31, h = l>>5;
  int sw = (blockIdx.x & 7)*96 + (blockIdx.x >> 3);   // 768 % 8 == 0
  const int rb = sw / 12, nb = sw % 12;
  const int brow = rb*128, bcol = nb*64;
  const int wr = (w>>1)*64, wc = (w&1)*32;

  f32x16 acc[2];
  #pragma unroll
  for (int i=0;i<2;i++)
    #pragma unroll
    for (int r=0;r<16;r++) acc[i][r] = 0.f;

  auto stage = [&](int buf, int kc){
    const u16* Ag = A  + ((size_t)(rb*KC_ + kc))*4096;
    const u16* Bg = BT + ((size_t)(nb*KC_ + kc))*2048;
    char* La = (char*)&lds[buf][0];
    char* Lb = (char*)&lds[buf][4096];
    #pragma unroll
    for (int it=0; it<2; ++it)
      gload_lds16(Ag + (it*256+t)*8, La + (it*256+t)*16);
    gload_lds16(Bg + t*8, Lb + t*16);
  };

  stage(0,0);
  int cur = 0;
  for (int kc=0; kc<KC_; ++kc){
    asm volatile("s_waitcnt vmcnt(0)\ns_barrier" ::: "memory");
    if (kc+1 < KC_) stage(cur^1, kc+1);
    const u16* La = &lds[cur][0];
    const u16* Lb = &lds[cur][4096];
    #pragma unroll
    for (int ks=0; ks<2; ++ks){
      bf16x8 af[2], bfr;
      #pragma unroll
      for (int mi=0;mi<2;mi++)
        af[mi] = *(const bf16x8*)(La + ((2*ks+h)*128 + wr + mi*32 + lq)*8);
      bfr = *(const bf16x8*)(Lb + ((2*ks+h)*64 + wc + lq)*8);
      __builtin_amdgcn_s_setprio(1);
      #pragma unroll
      for (int mi=0;mi<2;mi++)
        acc[mi] = mfma32(af[mi], bfr, acc[mi]);
      __builtin_amdgcn_s_setprio(0);
    }
    cur ^= 1;
  }

  {
    int n = bcol + wc + lq;
    float bs = bias[n];
    #pragma unroll
    for (int mi=0;mi<2;mi++)
      #pragma unroll
      for (int r=0;r<16;r++){
        int m = brow + wr + mi*32 + (r&3) + 8*(r>>2) + 4*h;
        fo[(size_t)m*NC_ + n] = acc[mi][r] + bs;
      }
  }
}

// ---------------- flash attention (r22, measured best): 16x16x32, 16 q/wave ----------
// Final plateau configuration: 768 blocks x 8 waves x 16 q, heavy-first bh map
// (chunk-lockstep L2 reuse, FETCH ~19MB), 2-buf 32KB top-barrier, pi-contiguous K/Q,
// sigma'-permuted V (PV A-frag = one contiguous 16B read), two 16-kv S^T tiles feed
// PV's B-operand IN-LANE, ones-MFMA lsum, no-max exp2 softmax.
__global__ __launch_bounds__(512,6) void attn_kernel(
    const u16* __restrict__ qg, const u16* __restrict__ kg,
    const u16* __restrict__ vg, u16* __restrict__ y)
{
  __shared__ u16 lds[2][8192];    // [buf][ K 4096 el | V 4096 el ], 32 KB
  const int t = threadIdx.x, w = t>>6, l = t&63;
  const int g = l>>4, lq16 = l&15;
  const int bid = blockIdx.x;
  const int qt = 15 - (bid/48);   // heaviest q-tiles first
  const int bh = bid % 48;
  const int bb = bh / NH_, hh = bh % NH_;
  const u16* qp = qg + (size_t)bh*NT_*ND_;
  const u16* kp = kg + (size_t)bh*NT_*ND_;    // slot-major chunked
  const u16* vp = vg + (size_t)bh*NT_*ND_;    // slot-major chunked, sigma'-permuted
  const int qw = qt*128 + w*16;   // this wave's 16-q base
  const int q = qw + lq16;        // this lane's q (column of S^T)

  // Q frags (pi-contiguous): Qf[b] element i holds Q[q][b*32 + g*8 + i]
  bf16x8 Qf[2];
  {
    const u16* qr = qp + (size_t)q*ND_ + g*8;
    Qf[0] = *(const bf16x8*)(qr);
    Qf[1] = *(const bf16x8*)(qr + 32);
  }
  bf16x8 ones;
  #pragma unroll
  for (int i=0;i<8;i++) ones[i] = (short)0x3F80;   // bf16 1.0

  f32x4 acc[4], ls;               // O^T acc per 16-d block (row d=g*4+r) + lsum
  #pragma unroll
  for (int i=0;i<4;i++)
    #pragma unroll
    for (int r=0;r<4;r++) acc[i][r] = 0.f;
  #pragma unroll
  for (int r=0;r<4;r++) ls[r] = 0.f;
  const int nc = 2*qt + 2;        // uniform across waves (skip handles tails)

  auto stage = [&](int buf, int c){
    const u16* kc2 = kp + c*4096;
    const u16* vc2 = vp + c*4096;
    gload_lds16(kc2 + t*8, (char*)&lds[buf][0]    + t*16);
    gload_lds16(vc2 + t*8, (char*)&lds[buf][4096] + t*16);
  };

  stage(0,0);
  int cur = 0;
  for (int c=0; c<nc; ++c){
    // waits only on stage(c) (one iteration old -> landed); stage(c+1) issued after
    asm volatile("s_waitcnt vmcnt(0)\ns_barrier" ::: "memory");
    if (c+1 < nc) stage(cur^1, c+1);

    const int kv0 = c*64;
    if (kv0 <= qw + 15){          // wave-uniform: skip fully-masked chunks
      const u16* Kb = &lds[cur][0];
      const u16* Vb = &lds[cur][4096];

      // S^T: 4 tiles of [16 kv x 16 q]; accumulate over 2 32-d blocks
      f32x4 s[4];
      #pragma unroll
      for (int t16=0;t16<4;t16++)
        #pragma unroll
        for (int r=0;r<4;r++) s[t16][r] = 0.f;
      __builtin_amdgcn_s_setprio(1);
      #pragma unroll
      for (int b=0;b<2;++b)
        #pragma unroll
        for (int t16=0;t16<4;++t16){
          bf16x8 kf = *(const bf16x8*)(Kb + ((b*4+g)*64 + t16*16 + lq16)*8);
          s[t16] = mfma16(kf, Qf[b], s[t16]);
        }
      __builtin_amdgcn_s_setprio(0);

      // causal mask: wave-uniform branch; diagonal chunks only
      if (kv0 + 63 > qw){
        #pragma unroll
        for (int t16=0;t16<4;++t16)
          #pragma unroll
          for (int r=0;r<4;++r){
            int kva = kv0 + t16*16 + g*4 + r;
            s[t16][r] = (kva <= q) ? s[t16][r] : -3e38f;
          }
      }

      // P = exp2(s); two PV B-frags: window u = tiles (2u, 2u+1) in-lane
      union { unsigned wd[4]; bf16x8 v; } pf[2];
      #pragma unroll
      for (int u=0;u<2;++u){
        pf[u].wd[0] = pkbf(exp2f(s[2*u][0]),   exp2f(s[2*u][1]));
        pf[u].wd[1] = pkbf(exp2f(s[2*u][2]),   exp2f(s[2*u][3]));
        pf[u].wd[2] = pkbf(exp2f(s[2*u+1][0]), exp2f(s[2*u+1][1]));
        pf[u].wd[3] = pkbf(exp2f(s[2*u+1][2]), exp2f(s[2*u+1][3]));
      }

      // PV + lsum: acc[db] += V^T-frag(u,db) * P(u);  ls += ones * P(u)
      __builtin_amdgcn_s_setprio(1);
      #pragma unroll
      for (int u=0;u<2;++u){
        #pragma unroll
        for (int db=0;db<4;++db){
          bf16x8 vf = *(const bf16x8*)(Vb + ((u*4+g)*64 + db*16 + lq16)*8);
          acc[db] = mfma16(vf, pf[u].v, acc[db]);
        }
        ls = mfma16(ones, pf[u].v, ls);
      }
      __builtin_amdgcn_s_setprio(0);
    }
    cur ^= 1;
  }

  float inv = 1.f / ls[0];        // full kv-sum for this lane's q

  // epilogue: y in 128-panel blocked layout: row m = bb*NT+q, k = hh*64 + db*16 + g*4 + r
  const int m = bb*NT_ + q;
  const int rbm = m>>7, rr = m&127;
  #pragma unroll
  for (int db=0; db<4; ++db){
    unsigned w0 = pkbf(acc[db][0]*inv, acc[db][1]*inv);
    unsigned w1 = pkbf(acc[db][2]*inv, acc[db][3]*inv);
    int k = hh*ND_ + db*16 + g*4;
    size_t off = (((size_t)rbm*KC_ + (k>>5))*4 + ((k>>3)&3))*1024 + rr*8 + (k&7);
    *(uint2*)(y + off) = make_uint2(w0, w1);
  }
}

// ---------------- launch ----------------
extern "C" void kernel_launch(void* const* d_in, const int* in_sizes, int n_in,
                              void* d_out, int out_size, void* d_ws, size_t ws_size,
                              hipStream_t stream) {
  const float* x  = (const float*)d_in[0];
  const float* wa = (const float*)d_in[1];
  const float* ba = (const float*)d_in[2];
  const float* wp = (const float*)d_in[3];
  const float* bp = (const float*)d_in[4];
  float* out = (float*)d_out;

  char* ws = (char*)d_ws;
  const size_t szXB = (size_t)NM_*NC_*2;        // 12,582,912
  const size_t szWA = (size_t)3*NC_*NC_*2;      //  3,538,944
  const size_t szWP = (size_t)NC_*NC_*2;        //  1,179,648
  const size_t szQ  = szXB;
  u16* xb  = (u16*)(ws);
  u16* wat = (u16*)(ws + szXB);
  u16* wpt = (u16*)(ws + szXB + szWA);
  u16* qb  = (u16*)(ws + szXB + szWA + szWP);
  u16* kb  = (u16*)((char*)qb + szQ);
  u16* vb  = (u16*)((char*)kb + szQ);
  u16* yb  = xb;    // reuse x-slot: attn writes y after gemmQ consumed xb

  // 1) fused preprocessing: cast x + transpose wa(96) + wp(64)  (one launch)
  prep_k<<<dim3(6144 + 1728 + 576), dim3(256), 0, stream>>>(x, wa, wp, xb, wat, wpt);
  // 2) qkv = x @ w_attn + b_attn  -> q*scale, k/v slot-major scattered (768 blocks)
  gemmQ<<<dim3(768), dim3(256), 0, stream>>>(xb, wat, ba, qb, kb, vb);
  // 3) flash attention -> y (blocked) bf16; 768 blocks x 8 waves x 16 q
  attn_kernel<<<dim3(NB_*NH_*(NT_/128)), dim3(512), 0, stream>>>(qb, kb, vb, yb);
  // 4) out = y @ w_proj + b_proj (f32); 768 blocks, exactly 3/CU
  gemmP<<<dim3(768), dim3(256), 0, stream>>>(yb, wpt, bp, out);
}